// Round 16
// baseline (160.260 us; speedup 1.0000x reference)
//
#include <hip/hip_runtime.h>

typedef __attribute__((ext_vector_type(4))) float float4v;
typedef __attribute__((ext_vector_type(2))) float float2v;
typedef __attribute__((ext_vector_type(8))) short short8;
typedef __attribute__((ext_vector_type(4))) float f32x4;

#define NEGV (-1000000000.0f)

// B=64, L=2048, E=512, Q=256; M = 131072, K = 512, N = 512
#define MTOT (64 * 2048)

__device__ __forceinline__ unsigned short f2bf(float f) {
    unsigned int u = __float_as_uint(f);
    u += 0x7fffu + ((u >> 16) & 1u);   // RNE round to bf16
    return (unsigned short)(u >> 16);
}

// async global->LDS, 16B per lane; LDS dest is WAVE-UNIFORM base + lane*16
// (m104: per-lane LDS addresses are ignored — only the global src is per-lane)
__device__ __forceinline__ void gload_lds16(const void* g, void* l) {
    __builtin_amdgcn_global_load_lds(
        (__attribute__((address_space(1))) unsigned int*)(unsigned long long)(g),
        (__attribute__((address_space(3))) unsigned int*)(unsigned int)(unsigned long long)(l),
        16, 0, 0);
}

// Wt[e][c] = bf16(W1[c][e]) via LDS 32x32 tile transpose.
__global__ __launch_bounds__(256)
void prep_wt_kernel(const float* __restrict__ W1, unsigned short* __restrict__ Wt) {
    __shared__ float t[32][33];
    int bx = blockIdx.x & 15;    // c tile
    int by = blockIdx.x >> 4;    // e tile
    int tx = threadIdx.x & 31;
    int ty = threadIdx.x >> 5;   // 0..7
    #pragma unroll
    for (int i = 0; i < 4; ++i)
        t[ty + 8 * i][tx] = W1[(bx * 32 + ty + 8 * i) * 512 + by * 32 + tx];
    __syncthreads();
    #pragma unroll
    for (int i = 0; i < 4; ++i)
        Wt[(by * 32 + ty + 8 * i) * 512 + bx * 32 + tx] = f2bf(t[tx][ty + 8 * i]);
}

// qc[b][e] = b1[e] + sum_q query[b][q] * W1[512+q][e]
__global__ void prep_qc_kernel(const float* __restrict__ query, const float* __restrict__ W1,
                               const float* __restrict__ b1, float* __restrict__ qc) {
    int b = blockIdx.x;
    int e = threadIdx.x;           // 256 threads -> cols e and e+256
    float acc0 = b1[e];
    float acc1 = b1[e + 256];
    const float* w = W1 + 512 * 512;
    #pragma unroll 8
    for (int q = 0; q < 256; ++q) {
        float qv = query[b * 256 + q];
        acc0 += qv * w[q * 512 + e];
        acc1 += qv * w[q * 512 + e + 256];
    }
    qc[b * 512 + e] = acc0;
    qc[b * 512 + e + 256] = acc1;
}

// Ab = bf16(enc) for valid 128-row tiles only (skipped tiles never read as
// live data; gemm may read them for masked rows — row-separable, harmless).
__global__ __launch_bounds__(256)
void prep_enc_kernel(const float* __restrict__ enc, const int* __restrict__ length,
                     unsigned short* __restrict__ Ab) {
    int bm = blockIdx.x;           // 0..1023
    int b = bm >> 4;
    if ((bm & 15) * 128 >= length[b]) return;
    long base = (long)bm * 128 * 512;
    const float* src = enc + base;
    unsigned short* dst = Ab + base;
    int tid = threadIdx.x;
    #pragma unroll 4
    for (int i = 0; i < 32; ++i) {
        long idx = (long)(i * 256 + tid) * 8;
        float4v a = *(const float4v*)(src + idx);
        float4v c = *(const float4v*)(src + idx + 4);
        union { unsigned short u[8]; short8 s; } o;
        o.u[0] = f2bf(a[0]); o.u[1] = f2bf(a[1]); o.u[2] = f2bf(a[2]); o.u[3] = f2bf(a[3]);
        o.u[4] = f2bf(c[0]); o.u[5] = f2bf(c[1]); o.u[6] = f2bf(c[2]); o.u[7] = f2bf(c[3]);
        *(short8*)(dst + idx) = o.s;
    }
}

// Compact valid 256-row tiles (512 total) into a worklist. meta[0]=count.
__global__ void build_wl_kernel(const int* __restrict__ length, int* __restrict__ wl,
                                int* __restrict__ meta) {
    int bm = blockIdx.x * 256 + threadIdx.x;   // 0..511
    int b = bm >> 3;
    if ((bm & 7) * 256 < length[b]) {
        int idx = atomicAdd(&meta[0], 1);
        wl[idx] = bm;
    }
}

// m201-class schedule: 256x256 tile, BK=32, 8 waves (2M x 4N, wave tile
// 128x64), 3-slot LDS ring (96KB), counted vmcnt(4) NEVER drained in-loop
// (T3+T4). Staging: per-instruction LDS region = wave-uniform (w*2+i)*1024
// + lane*16 (m104-compliant), source pre-swizzled for that linear offset.
__global__ __launch_bounds__(512)
void gemm_logits_kernel(const unsigned short* __restrict__ Ab,  // [M][512] bf16
                        const unsigned short* __restrict__ Wt,  // [512 n][512 k] bf16
                        const float* __restrict__ qc,           // [64][512]
                        const float* __restrict__ v,            // [512]
                        const int* __restrict__ wl,             // valid 256-tile list
                        int* __restrict__ meta,                 // [0]=n, [1]=ticket
                        float* __restrict__ part)               // [8][M] partials
{
    __shared__ unsigned short As[3 * 256 * 32];  // 3 x 16 KB
    __shared__ unsigned short Bs[3 * 256 * 32];  // 3 x 16 KB
    __shared__ int s_t;

    int tid = threadIdx.x;
    int lane = tid & 63;
    int w = tid >> 6;              // 0..7
    int wm = w >> 2, wn = w & 3;   // wave tile 128 x 64

    // staging: 2 instructions per wave per tile (A and B each); instruction i
    // covers LDS [(w*2+i)*1024, +1024), lane l at +l*16  [m104 pattern]
    int sA_off[2], sA_src[2];
    #pragma unroll
    for (int i = 0; i < 2; ++i) {
        int off = (w * 2 + i) * 1024 + lane * 16;   // linear LDS byte
        int r = off >> 6, kb = off & 63;            // 64B rows (32 bf16)
        sA_off[i] = off;
        sA_src[i] = r * 1024 + (kb ^ (((r >> 1) & 3) << 4));  // inverse swizzle
    }

    // fragment read byte offsets (within one 16KB slot)
    int aoff[2][4], boff[4];
    int kbase = (lane >> 4) * 16;
    #pragma unroll
    for (int mh = 0; mh < 2; ++mh)
        #pragma unroll
        for (int mi = 0; mi < 4; ++mi) {
            int ar = wm * 128 + mh * 64 + mi * 16 + (lane & 15);
            aoff[mh][mi] = ar * 64 + (kbase ^ (((ar >> 1) & 3) << 4));
        }
    #pragma unroll
    for (int ni = 0; ni < 4; ++ni) {
        int br = wn * 64 + ni * 16 + (lane & 15);
        boff[ni] = br * 64 + (kbase ^ (((br >> 1) & 3) << 4));
    }

    int nw = meta[0] * 2;          // 2 bn tickets per valid 256-tile

    if (tid == 0) s_t = atomicAdd(&meta[1], 1);
    __syncthreads();
    int t = s_t;

    while (t < nw) {
        int bm = wl[t >> 1];
        int bn = t & 1;
        int b = bm >> 3;
        long row0 = (long)bm * 256;
        int col0 = bn * 256;

        const char* gA = (const char*)Ab + row0 * 1024;
        const char* gB = (const char*)Wt + (long)col0 * 1024;

        f32x4 acc[8][4] = {};

#define ISS_A(t_, sI) do {                                                   \
    char* l_ = (char*)As + (sI) * 16384;                                     \
    gload_lds16(gA + sA_src[0] + (t_) * 64, l_ + sA_off[0]);                 \
    gload_lds16(gA + sA_src[1] + (t_) * 64, l_ + sA_off[1]);                 \
} while (0)

#define ISS_B(t_, sI) do {                                                   \
    char* l_ = (char*)Bs + (sI) * 16384;                                     \
    gload_lds16(gB + sA_src[0] + (t_) * 64, l_ + sA_off[0]);                 \
    gload_lds16(gB + sA_src[1] + (t_) * 64, l_ + sA_off[1]);                 \
} while (0)

#define MFMA_HALF(mh) do {                                                   \
    _Pragma("unroll")                                                        \
    for (int mi = 0; mi < 4; ++mi)                                           \
        _Pragma("unroll")                                                    \
        for (int ni = 0; ni < 4; ++ni)                                       \
            acc[(mh) * 4 + mi][ni] =                                         \
                __builtin_amdgcn_mfma_f32_16x16x32_bf16(af_[mi], bf_[ni],    \
                    acc[(mh) * 4 + mi][ni], 0, 0, 0);                        \
} while (0)

#define KITER(t_, sC, sI, ISS, VM) do {                                      \
    asm volatile("s_waitcnt vmcnt(" #VM ")" ::: "memory");                   \
    __builtin_amdgcn_s_barrier();                                            \
    asm volatile("" ::: "memory");                                           \
    {                                                                        \
        const char* as_ = (const char*)As + (sC) * 16384;                    \
        const char* bs_ = (const char*)Bs + (sC) * 16384;                    \
        short8 af_[4], bf_[4];                                               \
        if (ISS) ISS_A((t_) + 2, sI);                                        \
        _Pragma("unroll")                                                    \
        for (int ni = 0; ni < 4; ++ni) bf_[ni] = *(const short8*)(bs_ + boff[ni]); \
        _Pragma("unroll")                                                    \
        for (int mi = 0; mi < 4; ++mi) af_[mi] = *(const short8*)(as_ + aoff[0][mi]); \
        __builtin_amdgcn_s_setprio(1);                                       \
        MFMA_HALF(0);                                                        \
        __builtin_amdgcn_s_setprio(0);                                       \
        if (ISS) ISS_B((t_) + 2, sI);                                        \
        _Pragma("unroll")                                                    \
        for (int mi = 0; mi < 4; ++mi) af_[mi] = *(const short8*)(as_ + aoff[1][mi]); \
        __builtin_amdgcn_s_setprio(1);                                       \
        MFMA_HALF(1);                                                        \
        __builtin_amdgcn_s_setprio(0);                                       \
    }                                                                        \
    asm volatile("" ::: "memory");                                           \
    __builtin_amdgcn_s_barrier();                                            \
} while (0)

        // prologue: fill ring slots 0,1 (8 loads/wave in flight)
        ISS_A(0, 0); ISS_B(0, 0);
        ISS_A(1, 1); ISS_B(1, 1);

        KITER(0,  0, 2, 1, 4);
        KITER(1,  1, 0, 1, 4);
        KITER(2,  2, 1, 1, 4);
        KITER(3,  0, 2, 1, 4);
        KITER(4,  1, 0, 1, 4);
        KITER(5,  2, 1, 1, 4);
        KITER(6,  0, 2, 1, 4);
        KITER(7,  1, 0, 1, 4);
        KITER(8,  2, 1, 1, 4);
        KITER(9,  0, 2, 1, 4);
        KITER(10, 1, 0, 1, 4);
        KITER(11, 2, 1, 1, 4);
        KITER(12, 0, 2, 1, 4);
        KITER(13, 1, 0, 1, 4);
        KITER(14, 2, 0, 0, 4);     // no issue; tile 15's loads still in flight
        KITER(15, 0, 0, 0, 0);     // tail drain

        // prefetch next ticket; atomic hides under epilogue
        if (tid == 0) s_t = atomicAdd(&meta[1], 1);

        // epilogue: u = tanh(acc + qc), 64-col partial via 16-lane reduce,
        // store into slice (bn*4 + wn) — unique writer per (slice,row).
        const float* qcb = qc + b * 512;
        float vcol[4], qcol[4];
        #pragma unroll
        for (int ni = 0; ni < 4; ++ni) {
            int c = col0 + wn * 64 + ni * 16 + (lane & 15);
            vcol[ni] = v[c];
            qcol[ni] = qcb[c];
        }
        float* pslice = part + (bn * 4 + wn) * MTOT + row0;
        #pragma unroll
        for (int mi = 0; mi < 8; ++mi) {
            #pragma unroll
            for (int j2 = 0; j2 < 4; ++j2) {
                float s = 0.f;
                #pragma unroll
                for (int ni = 0; ni < 4; ++ni) {
                    float xx = acc[mi][ni][j2] + qcol[ni];
                    float e2 = __expf(2.0f * xx);
                    float tt = 1.0f - 2.0f * __builtin_amdgcn_rcpf(e2 + 1.0f);
                    s += tt * vcol[ni];
                }
                s += __shfl_xor(s, 1);
                s += __shfl_xor(s, 2);
                s += __shfl_xor(s, 4);
                s += __shfl_xor(s, 8);
                if ((lane & 15) == 0)
                    pslice[wm * 128 + mi * 16 + 4 * (lane >> 4) + j2] = s;
            }
        }
        __syncthreads();           // all waves see s_t; LDS safe for next ticket
        t = s_t;
    }
}

// masked softmax per batch row; sums 8 slices; zeroes ctx[b]
__global__ void softmax_kernel(const float* __restrict__ part, const int* __restrict__ length,
                               float* __restrict__ att, float* __restrict__ ctx) {
    int b = blockIdx.x;
    int len = length[b];
    int tid = threadIdx.x;     // 256
    int lane = tid & 63, wv = tid >> 6;
    const float* p0 = part + b * 2048;
    float* ab = att + b * 2048;

    ctx[b * 512 + tid] = 0.f;
    ctx[b * 512 + 256 + tid] = 0.f;

    float vals[8];
    float mymax = -3.402823466e38f;
    #pragma unroll
    for (int i = 0; i < 8; ++i) {
        int l = tid + i * 256;
        float xv = NEGV;
        if (l < len) {
            xv = 0.f;
            #pragma unroll
            for (int s = 0; s < 8; ++s)
                xv += p0[s * MTOT + l];
        }
        vals[i] = xv;
        mymax = fmaxf(mymax, xv);
    }
    #pragma unroll
    for (int m = 32; m; m >>= 1) mymax = fmaxf(mymax, __shfl_xor(mymax, m));
    __shared__ float sm[4];
    if (lane == 0) sm[wv] = mymax;
    __syncthreads();
    float bmax = fmaxf(fmaxf(sm[0], sm[1]), fmaxf(sm[2], sm[3]));

    float mysum = 0.f;
    #pragma unroll
    for (int i = 0; i < 8; ++i) {
        int l = tid + i * 256;
        float e = (l < len) ? __expf(vals[i] - bmax) : 0.f;
        vals[i] = e;
        mysum += e;
    }
    #pragma unroll
    for (int m = 32; m; m >>= 1) mysum += __shfl_xor(mysum, m);
    __shared__ float ss[4];
    if (lane == 0) ss[wv] = mysum;
    __syncthreads();
    float tot = ss[0] + ss[1] + ss[2] + ss[3];
    float inv = 1.0f / (tot + 1e-5f);
    #pragma unroll
    for (int i = 0; i < 8; ++i) {
        int l = tid + i * 256;
        ab[l] = vals[i] * inv;
    }
}

// context[b][e] = sum_l att[b][l] * Ab[b][l][e] (bf16 enc copy; half the bytes)
__global__ void ctx_kernel(const float* __restrict__ att, const unsigned short* __restrict__ Ab,
                           const int* __restrict__ length, float* __restrict__ ctx) {
    int b = blockIdx.x;        // 64
    int lc = blockIdx.y;       // 16 chunks of 128
    int len = length[b];
    int l0 = lc * 128;
    if (l0 >= len) return;
    int lim = len - l0;
    if (lim > 128) lim = 128;

    int t = threadIdx.x;       // 256 -> 2 cols each
    const float* ab = att + b * 2048 + l0;
    const unsigned short* eb = Ab + ((long)(b * 2048 + l0)) * 512 + t * 2;
    float c0 = 0.f, c1 = 0.f;
    #pragma unroll 4
    for (int l = 0; l < lim; ++l) {
        float a = ab[l];
        unsigned int wv = *(const unsigned int*)(eb);
        eb += 512;
        c0 += a * __uint_as_float(wv << 16);
        c1 += a * __uint_as_float(wv & 0xffff0000u);
    }
    atomicAdd(&ctx[b * 512 + 2 * t], c0);
    atomicAdd(&ctx[b * 512 + 2 * t + 1], c1);
}

extern "C" void kernel_launch(void* const* d_in, const int* in_sizes, int n_in,
                              void* d_out, int out_size, void* d_ws, size_t ws_size,
                              hipStream_t stream) {
    const float* enc    = (const float*)d_in[0];   // [64,2048,512]
    const float* query  = (const float*)d_in[1];   // [64,256]
    const int*   length = (const int*)d_in[2];     // [64]
    const float* W1     = (const float*)d_in[3];   // [768,512]
    const float* b1     = (const float*)d_in[4];   // [512]
    const float* v      = (const float*)d_in[5];   // [512]

    float* out = (float*)d_out;
    float* ctx = out;                // [64,512]
    float* att = out + 64 * 512;     // [64,2048]

    char* ws = (char*)d_ws;
    float* part        = (float*)ws;                               // 8*M f32 = 4MB
    float* qc          = (float*)(ws + 8L * MTOT * 4);             // 128KB
    unsigned short* Wt = (unsigned short*)(ws + 8L * MTOT * 4 + 64 * 512 * 4); // 512KB
    int* wl            = (int*)(ws + 8L * MTOT * 4 + 64 * 512 * 4 + 512 * 1024); // 4KB
    int* meta          = (int*)(ws + 8L * MTOT * 4 + 64 * 512 * 4 + 512 * 1024 + 4096); // 8B
    unsigned short* Ab = (unsigned short*)(ws + 8L * MTOT * 4 + 64 * 512 * 4 + 512 * 1024 + 8192); // 128MB

    hipMemsetAsync(meta, 0, 8, stream);
    prep_wt_kernel<<<256, 256, 0, stream>>>(W1, Wt);
    prep_qc_kernel<<<64, 256, 0, stream>>>(query, W1, b1, qc);
    build_wl_kernel<<<2, 256, 0, stream>>>(length, wl, meta);
    prep_enc_kernel<<<1024, 256, 0, stream>>>(enc, length, Ab);

    gemm_logits_kernel<<<256, 512, 0, stream>>>(Ab, Wt, qc, v, wl, meta, part);

    softmax_kernel<<<64, 256, 0, stream>>>(part, length, att, ctx);

    dim3 g3(64, 16);
    ctx_kernel<<<g3, 256, 0, stream>>>(att, Ab, length, ctx);
}

// Round 17
// 136.468 us; speedup vs baseline: 1.1743x; 1.1743x over previous
//
#include <hip/hip_runtime.h>

typedef __attribute__((ext_vector_type(4))) float float4v;
typedef __attribute__((ext_vector_type(2))) float float2v;
typedef __attribute__((ext_vector_type(8))) short short8;
typedef __attribute__((ext_vector_type(4))) float f32x4;

#define NEGV (-1000000000.0f)

// B=64, L=2048, E=512, Q=256; M = 131072, K = 512, N = 512
#define MTOT (64 * 2048)

__device__ __forceinline__ unsigned short f2bf(float f) {
    unsigned int u = __float_as_uint(f);
    u += 0x7fffu + ((u >> 16) & 1u);   // RNE round to bf16
    return (unsigned short)(u >> 16);
}

// async global->LDS, 16B per lane; LDS dest = wave-uniform base + lane*16
__device__ __forceinline__ void gload_lds16(const void* g, void* l) {
    __builtin_amdgcn_global_load_lds(
        (__attribute__((address_space(1))) unsigned int*)(unsigned long long)(g),
        (__attribute__((address_space(3))) unsigned int*)(unsigned int)(unsigned long long)(l),
        16, 0, 0);
}

// Wt[e][c] = bf16(W1[c][e]) via LDS 32x32 tile transpose.
__global__ __launch_bounds__(256)
void prep_wt_kernel(const float* __restrict__ W1, unsigned short* __restrict__ Wt) {
    __shared__ float t[32][33];
    int bx = blockIdx.x & 15;    // c tile
    int by = blockIdx.x >> 4;    // e tile
    int tx = threadIdx.x & 31;
    int ty = threadIdx.x >> 5;   // 0..7
    #pragma unroll
    for (int i = 0; i < 4; ++i)
        t[ty + 8 * i][tx] = W1[(bx * 32 + ty + 8 * i) * 512 + by * 32 + tx];
    __syncthreads();
    #pragma unroll
    for (int i = 0; i < 4; ++i)
        Wt[(by * 32 + ty + 8 * i) * 512 + bx * 32 + tx] = f2bf(t[tx][ty + 8 * i]);
}

// qc[b][e] = b1[e] + sum_q query[b][q] * W1[512+q][e]; also zeroes ctxraw/S.
__global__ void prep_qc_kernel(const float* __restrict__ query, const float* __restrict__ W1,
                               const float* __restrict__ b1, float* __restrict__ qc,
                               float* __restrict__ ctxraw, float* __restrict__ S) {
    int b = blockIdx.x;
    int e = threadIdx.x;           // 256 threads -> cols e and e+256
    ctxraw[b * 512 + e] = 0.f;
    ctxraw[b * 512 + 256 + e] = 0.f;
    if (e == 0) S[b] = 0.f;
    float acc0 = b1[e];
    float acc1 = b1[e + 256];
    const float* w = W1 + 512 * 512;
    #pragma unroll 8
    for (int q = 0; q < 256; ++q) {
        float qv = query[b * 256 + q];
        acc0 += qv * w[q * 512 + e];
        acc1 += qv * w[q * 512 + e + 256];
    }
    qc[b * 512 + e] = acc0;
    qc[b * 512 + e + 256] = acc1;
}

// R10's proven BM=128 x BN=512 (full N) gemm, BK=32, 16 waves, dbuf-2,
// A reg-staged f32->bf16 (swizzled ds_write), B via global_load_lds.
// FUSED epilogue: logits complete in-block -> w = exp(logit) (no max-sub
// needed: |logit| <= sum|v| ~ 25, exp can't overflow f32; EPS shift is
// <=1e-5 relative) -> raw w to att, sum-atomics into S[b], and
// ctx_raw[b][e] += sum_l w[l]*enc[l][e] from the L2-hot A tile.
__global__ __launch_bounds__(1024)
void gemm_fused_kernel(const float* __restrict__ A,             // encoded [M][512] f32
                       const unsigned short* __restrict__ Wt,   // [512 n][512 k] bf16
                       const float* __restrict__ qc,            // [64][512]
                       const float* __restrict__ v,             // [512]
                       const int* __restrict__ length,          // [64]
                       float* __restrict__ att,                 // [M] raw w out
                       float* __restrict__ ctxraw,              // [64][512] accum
                       float* __restrict__ S)                   // [64] sum accum
{
    int bm = blockIdx.x;           // 0..1023 row tile
    int b = bm >> 4;
    int len = length[b];
    int l0 = (bm & 15) * 128;
    if (l0 >= len) return;         // fully-masked tile

    __shared__ unsigned short As[2][128 * 32];   // 2 x 8 KB, swizzled
    __shared__ unsigned short Bs[2][512 * 32];   // 2 x 32 KB, swizzled
    __shared__ float lred[128][8];
    __shared__ float wbuf[128];

    int tid = threadIdx.x;
    int lane = tid & 63;
    int w = tid >> 6;              // 0..15
    int wm = w >> 3, wn = w & 7;   // 2 x 8 wave grid; wave tile 64x64
    long row0 = (long)bm * 128;

    // --- A reg-staging: thread -> row r = tid>>3, k-eighth e8 = tid&7 (16B) ---
    int ar_r = tid >> 3;
    int ar_e = tid & 7;
    const char* gAr = (const char*)A + (row0 + ar_r) * 2048 + ar_e * 16;
    int awr = ar_r * 64 + ((ar_e * 8) ^ (((ar_r >> 1) & 3) << 4));

    // --- B staging: linear LDS dest (wave base + lane*16), pre-swizzled src ---
    int offw = w * 2048 + lane * 16;             // this wave's 2KB of 32KB slot
    const char* gB0;
    const char* gB1;
    {
        int o = offw;
        int r = o >> 6;
        gB0 = (const char*)Wt + r * 1024 + ((o & 63) ^ (((r >> 1) & 3) << 4));
        o = offw + 1024;
        r = o >> 6;
        gB1 = (const char*)Wt + r * 1024 + ((o & 63) ^ (((r >> 1) & 3) << 4));
    }

    // --- fragment read byte offsets (within one slot) ---
    int aoff[4], boff[4];
    int kb = 16 * (lane >> 4);
    #pragma unroll
    for (int mi = 0; mi < 4; ++mi) {
        int ar = wm * 64 + (lane & 15) + mi * 16;
        aoff[mi] = ar * 64 + (kb ^ (((ar >> 1) & 3) << 4));
    }
    #pragma unroll
    for (int ni = 0; ni < 4; ++ni) {
        int br = wn * 64 + (lane & 15) + ni * 16;
        boff[ni] = br * 64 + (kb ^ (((br >> 1) & 3) << 4));
    }

    f32x4 acc[4][4] = {};
    float4v P;

#define GISSUE(t, sI) do {                                                   \
    P = *(const float4v*)(gAr + (t) * 128);                                  \
    char* lb_ = (char*)(&Bs[0][0]) + (sI) * 32768 + offw;                    \
    gload_lds16(gB0 + (t) * 64, lb_);                                        \
    gload_lds16(gB1 + (t) * 64, lb_ + 1024);                                 \
} while (0)

#define CVTW(sW) do {                                                        \
    union { unsigned int u[2]; unsigned long long ll; } pk_;                 \
    pk_.u[0] = (unsigned int)f2bf(P[0]) | ((unsigned int)f2bf(P[1]) << 16);  \
    pk_.u[1] = (unsigned int)f2bf(P[2]) | ((unsigned int)f2bf(P[3]) << 16);  \
    *(unsigned long long*)((char*)(&As[0][0]) + (sW) * 8192 + awr) = pk_.ll; \
} while (0)

#define KCOMP(sC) do {                                                       \
    const char* as_ = (const char*)(&As[0][0]) + (sC) * 8192;                \
    const char* bs_ = (const char*)(&Bs[0][0]) + (sC) * 32768;               \
    short8 af_[4];                                                           \
    _Pragma("unroll")                                                        \
    for (int mi = 0; mi < 4; ++mi) af_[mi] = *(const short8*)(as_ + aoff[mi]); \
    _Pragma("unroll")                                                        \
    for (int ni = 0; ni < 4; ++ni) {                                         \
        short8 bf_ = *(const short8*)(bs_ + boff[ni]);                       \
        _Pragma("unroll")                                                    \
        for (int mi = 0; mi < 4; ++mi)                                       \
            acc[mi][ni] = __builtin_amdgcn_mfma_f32_16x16x32_bf16(af_[mi], bf_, acc[mi][ni], 0, 0, 0); \
    }                                                                        \
} while (0)

#define KITER(t) do {                                                        \
    GISSUE((t) + 1, ((t) + 1) & 1);                                          \
    KCOMP((t) & 1);                                                          \
    asm volatile("s_waitcnt vmcnt(2)" ::: "memory");                         \
    CVTW(((t) + 1) & 1);                                                     \
    asm volatile("s_waitcnt vmcnt(0) lgkmcnt(0)" ::: "memory");              \
    __builtin_amdgcn_s_barrier();                                            \
    asm volatile("" ::: "memory");                                           \
} while (0)

    // prologue: stage K-step 0 into slot 0
    GISSUE(0, 0);
    asm volatile("s_waitcnt vmcnt(2)" ::: "memory");   // A regs landed
    CVTW(0);
    asm volatile("s_waitcnt vmcnt(0) lgkmcnt(0)" ::: "memory");
    __builtin_amdgcn_s_barrier();
    asm volatile("" ::: "memory");

    KITER(0);  KITER(1);  KITER(2);  KITER(3);
    KITER(4);  KITER(5);  KITER(6);  KITER(7);
    KITER(8);  KITER(9);  KITER(10); KITER(11);
    KITER(12); KITER(13); KITER(14);
    KCOMP(1);                                          // t = 15

    // epilogue: u = tanh(acc + qc), per-wave 64-col partial via 16-lane
    // reduce, then in-block reduce over the 8 wn waves in LDS.
    const float* qcb = qc + b * 512;
    float vcol[4], qcol[4];
    #pragma unroll
    for (int ni = 0; ni < 4; ++ni) {
        int c = wn * 64 + ni * 16 + (lane & 15);
        vcol[ni] = v[c];
        qcol[ni] = qcb[c];
    }
    #pragma unroll
    for (int mi = 0; mi < 4; ++mi) {
        #pragma unroll
        for (int j2 = 0; j2 < 4; ++j2) {
            float s = 0.f;
            #pragma unroll
            for (int ni = 0; ni < 4; ++ni) {
                float xx = acc[mi][ni][j2] + qcol[ni];
                float e2 = __expf(2.0f * xx);
                float tt = 1.0f - 2.0f * __builtin_amdgcn_rcpf(e2 + 1.0f);
                s += tt * vcol[ni];
            }
            s += __shfl_xor(s, 1);
            s += __shfl_xor(s, 2);
            s += __shfl_xor(s, 4);
            s += __shfl_xor(s, 8);
            if ((lane & 15) == 0)
                lred[wm * 64 + mi * 16 + 4 * (lane >> 4) + j2][wn] = s;
        }
    }
    __syncthreads();

    // fused: w = exp(logit) (0 beyond length), raw w -> att, sum -> S[b]
    if (tid < 128) {
        float lg = 0.f;
        #pragma unroll
        for (int q = 0; q < 8; ++q) lg += lred[tid][q];
        float wf = (l0 + tid < len) ? __expf(lg) : 0.f;
        att[row0 + tid] = wf;
        wbuf[tid] = wf;
        float s = wf;
        #pragma unroll
        for (int m = 32; m; m >>= 1) s += __shfl_xor(s, m);
        if ((tid & 63) == 0) atomicAdd(&S[b], s);
    }
    __syncthreads();

    // fused ctx: thread covers e = tid&511, l-half = tid>>9 (L2-hot A tile)
    {
        int e = tid & 511;
        int lh = tid >> 9;                 // 0 or 1
        const float* encb = A + (row0 + lh * 64) * 512 + e;
        const float* wb = &wbuf[lh * 64];
        float c = 0.f;
        #pragma unroll 4
        for (int l = 0; l < 64; ++l)
            c += wb[l] * encb[l * 512];
        atomicAdd(&ctxraw[b * 512 + e], c);
    }
}

// normalize: att[l] = (l<len) ? w[l]/S[b] : 0 ; ctx = ctxraw/S[b]
__global__ void norm_kernel(const float* __restrict__ S, const int* __restrict__ length,
                            const float* __restrict__ ctxraw,
                            float* __restrict__ att, float* __restrict__ ctx) {
    int b = blockIdx.x;
    int tid = threadIdx.x;     // 256
    float inv = 1.0f / S[b];
    ctx[b * 512 + tid] = ctxraw[b * 512 + tid] * inv;
    ctx[b * 512 + 256 + tid] = ctxraw[b * 512 + 256 + tid] * inv;
    int len = length[b];
    float* ab = att + b * 2048;
    #pragma unroll
    for (int i = 0; i < 8; ++i) {
        int l = tid + i * 256;
        float wv = ab[l];
        ab[l] = (l < len) ? wv * inv : 0.f;
    }
}

extern "C" void kernel_launch(void* const* d_in, const int* in_sizes, int n_in,
                              void* d_out, int out_size, void* d_ws, size_t ws_size,
                              hipStream_t stream) {
    const float* enc    = (const float*)d_in[0];   // [64,2048,512]
    const float* query  = (const float*)d_in[1];   // [64,256]
    const int*   length = (const int*)d_in[2];     // [64]
    const float* W1     = (const float*)d_in[3];   // [768,512]
    const float* b1     = (const float*)d_in[4];   // [512]
    const float* v      = (const float*)d_in[5];   // [512]

    float* out = (float*)d_out;
    float* ctx = out;                // [64,512]
    float* att = out + 64 * 512;     // [64,2048]

    char* ws = (char*)d_ws;
    float* qc          = (float*)ws;                               // 128KB
    unsigned short* Wt = (unsigned short*)(ws + 64 * 512 * 4);     // 512KB
    float* ctxraw      = (float*)(ws + 64 * 512 * 4 + 512 * 1024); // 128KB
    float* S           = (float*)(ws + 64 * 512 * 4 + 512 * 1024 + 64 * 512 * 4); // 256B

    prep_wt_kernel<<<256, 256, 0, stream>>>(W1, Wt);
    prep_qc_kernel<<<64, 256, 0, stream>>>(query, W1, b1, qc, ctxraw, S);

    gemm_fused_kernel<<<1024, 1024, 0, stream>>>(enc, Wt, qc, v, length, att, ctxraw, S);

    norm_kernel<<<64, 256, 0, stream>>>(S, length, ctxraw, att, ctx);
}